// Round 23
// baseline (67.763 us; speedup 1.0000x reference)
//
#include <hip/hip_runtime.h>

namespace {

constexpr int B = 4, S = 4096, H = 16, D = 32;
constexpr int L = 32;             // chunk length
constexpr int NC = S / L;         // 128 chunks per sequence
constexpr int NBH = B * H;        // 64
constexpr int RS = H * D;         // 512 floats between consecutive time steps
constexpr float GEPS = 1.52587890625e-05f;  // 2^-16 per-step decay clamp

// Lore (rounds 6-22, measured):
//  - launch_bounds(256,w) caps VGPR ~256/w; cap < live set => GB-scale spill.
//  - Scalar j-loops over LDS tiles are LDS-instruction bound -> MFMA.
//  - COLD scalar column loads are latency death (r13); OK L3-warm (r12).
//  - Pure consumers beat recomputing consumers for STATE (r16-19), but
//    moving per-chunk W/l exports producer-side just conserves k1+k3 sum
//    (r20-22 all ~62us). The real lever is SCHEDULE: r16's kA ran k1's
//    whole workload at ~12-16us via 16-chunks-per-block sequential loop
//    with loads issued at loop-top (cross-iteration latency hiding).
//  - Same-wave LDS ([wv] slots) needs NO block barrier (r18/r19 verified).
//  - NEVER quantize l below f32 (r21 absmax 1.5); scales/W in bf16 are fine.
//  - MFMA operand convention (HW-verified r12, absmax 0.5):
//    A-op: row = lane&31, k = 8*(lane>>5)+e (+16 for 2nd MFMA)
//    B-op: col = lane&31, same k
//    C/D : col = lane&31, row = (reg&3)+8*(reg>>2)+4*(lane>>5)

typedef __attribute__((ext_vector_type(8)))  short short8v;   // 8 bf16 = 4 VGPR
typedef __attribute__((ext_vector_type(16))) float f32x16;    // 16 f32 acc

__device__ __forceinline__ float flog2(float x) { return __builtin_amdgcn_logf(x); }
__device__ __forceinline__ float fexp2(float x) { return __builtin_amdgcn_exp2f(x); }
__device__ __forceinline__ unsigned f2bfu(float f) {          // fp32 -> bf16 (RNE)
    unsigned u = __float_as_uint(f);
    return (u + 0x7FFFu + ((u >> 16) & 1u)) >> 16;
}
__device__ __forceinline__ short f2bf(float f) { return (short)f2bfu(f); }
__device__ __forceinline__ float bf2f(short s) {              // bf16 -> fp32
    return __uint_as_float(((unsigned)(ushort)s) << 16);
}

// ---------------- Kernel 1: sequential-chunk producer (kA schedule) ----------
// 512 blocks x 16 chunks sequential. Loads at loop-top hide HBM latency under
// previous iteration's compute; wave 0's MFMA tail overlaps waves 1-3 prefetch.
// W = v*2^{total-l} (TOTAL-scaled);  ChKV[chunk] bf16;  ChG[chunk] = 2^{total}.
__global__ __launch_bounds__(256)
void k1_seq(const float* __restrict__ Kp, const float* __restrict__ Vp,
            const float* __restrict__ Gp, ushort* __restrict__ ChKV,
            float* __restrict__ ChG)
{
    __shared__ __align__(16) float  k_s[L][36];
    __shared__ __align__(16) float  lg[L][36];
    __shared__ __align__(16) ushort w_s[L][40];
    __shared__ float sub[8][D];
    __shared__ float totr[D];

    const int blk = blockIdx.x;              // bh*8 + seg
    const int bh = blk >> 3, seg = blk & 7;
    const int b = bh >> 4, h = bh & (H - 1);

    const int tid = threadIdx.x;
    const int i = tid >> 3;                  // row 0..31
    const int u = (tid & 7) * 4;             // col quad
    const int m = tid & 31, t = tid >> 5;    // scan mapping
    const int r0 = t * 4;

    for (int cc = 0; cc < 16; ++cc) {
        const int c = seg * 16 + cc;
        const int chunk = bh * NC + c;
        const long base = ((long)b * S + (long)c * L) * RS + h * D;
        const long roff = base + (long)i * RS + u;
        float4 k4 = *(const float4*)(Kp + roff);       // issued before barrier:
        float4 v4 = *(const float4*)(Vp + roff);       // overlaps prev compute
        float4 g4 = *(const float4*)(Gp + roff);
        __syncthreads();                     // prev iteration LDS consumed
        *(float4*)&k_s[i][u] = k4;
        float4 lv;
        lv.x = flog2(fmaxf(g4.x, GEPS));
        lv.y = flog2(fmaxf(g4.y, GEPS));
        lv.z = flog2(fmaxf(g4.z, GEPS));
        lv.w = flog2(fmaxf(g4.w, GEPS));
        *(float4*)&lg[i][u] = lv;
        __syncthreads();                     // b1

        float c0 = lg[r0 + 0][m];
        float c1 = c0 + lg[r0 + 1][m];
        float c2 = c1 + lg[r0 + 2][m];
        float c3 = c2 + lg[r0 + 3][m];
        sub[t][m] = c3;
        __syncthreads();                     // b2

        {
            float sb[8];
            float total = 0.f;
            #pragma unroll
            for (int tt = 0; tt < 8; ++tt) { sb[tt] = sub[tt][m]; total += sb[tt]; }
            float base_l = 0.f;
            #pragma unroll
            for (int tt = 0; tt < 8; ++tt) { if (tt < t) base_l += sb[tt]; }
            lg[r0 + 0][m] = base_l + c0;
            lg[r0 + 1][m] = base_l + c1;
            lg[r0 + 2][m] = base_l + c2;
            lg[r0 + 3][m] = base_l + c3;
            if (t == 0) totr[m] = total;
            if (t == 1) ChG[(long)chunk * D + m] = fexp2(total);
        }
        __syncthreads();                     // b3

        // W = v * 2^{total - l}  (exponent <= 0), v4 still in registers
        {
            float4 l4 = *(float4*)&lg[i][u];
            float4 t4 = *(float4*)&totr[u];
            unsigned p0 = f2bfu(v4.x * fexp2(t4.x - l4.x))
                        | (f2bfu(v4.y * fexp2(t4.y - l4.y)) << 16);
            unsigned p1 = f2bfu(v4.z * fexp2(t4.z - l4.z))
                        | (f2bfu(v4.w * fexp2(t4.w - l4.w)) << 16);
            uint2 pp; pp.x = p0; pp.y = p1;
            *(uint2*)&w_s[i][u] = pp;
        }
        __syncthreads();                     // b4

        // wave 0: 2 MFMAs + bf16 store (waves 1-3 run ahead to next loads)
        if (tid < 64) {
            const int half = tid >> 5;
            const int mm = tid & 31;
            short8v ka0, ka1, wf0, wf1;
            #pragma unroll
            for (int e = 0; e < 8; ++e) {
                ka0[e] = f2bf(k_s[8 * half + e][mm]);
                ka1[e] = f2bf(k_s[16 + 8 * half + e][mm]);
                wf0[e] = (short)w_s[8 * half + e][mm];
                wf1[e] = (short)w_s[16 + 8 * half + e][mm];
            }
            f32x16 acc;
            #pragma unroll
            for (int e = 0; e < 16; ++e) acc[e] = 0.f;
            acc = __builtin_amdgcn_mfma_f32_32x32x16_bf16(ka0, wf0, acc, 0, 0, 0);
            acc = __builtin_amdgcn_mfma_f32_32x32x16_bf16(ka1, wf1, acc, 0, 0, 0);

            ushort* kvout = ChKV + (long)chunk * (D * D);
            #pragma unroll
            for (int reg = 0; reg < 16; ++reg) {
                const int d = (reg & 3) + 8 * (reg >> 2) + 4 * half;
                kvout[d * D + mm] = (ushort)f2bf(acc[reg]);
            }
        }
    }
}

// ---------------- Kernel 2: inter-chunk scan (bf16 in/out, f32 state) --------
__global__ __launch_bounds__(256)
void k2_scan(ushort* __restrict__ ChKV, const float* __restrict__ ChG)
{
    const int bh = blockIdx.x >> 2;
    const int dg = blockIdx.x & 3;
    const int tid = threadIdx.x;
    const int d = dg * 8 + (tid >> 5);
    const int m = tid & 31;

    const long kvoff = (long)bh * NC * (D * D) + d * D + m;
    const long goff = (long)bh * NC * D + m;

    ushort ka[8]; float ga[8];
    #pragma unroll
    for (int t = 0; t < 8; ++t) {
        ka[t] = ChKV[kvoff + (long)t * (D * D)];
        ga[t] = ChG[goff + (long)t * D];
    }
    float st = 0.f;
    for (int c0 = 0; c0 < NC; c0 += 8) {
        ushort kb[8]; float gb2[8];
        const bool more = (c0 + 8) < NC;
        #pragma unroll
        for (int t = 0; t < 8; ++t) {
            kb[t]  = more ? ChKV[kvoff + (long)(c0 + 8 + t) * (D * D)] : (ushort)0;
            gb2[t] = more ? ChG[goff + (long)(c0 + 8 + t) * D] : 0.f;
        }
        #pragma unroll
        for (int t = 0; t < 8; ++t) {
            ChKV[kvoff + (long)(c0 + t) * (D * D)] = (ushort)f2bf(st); // START
            st = ga[t] * st + bf2f((short)ka[t]);
        }
        #pragma unroll
        for (int t = 0; t < 8; ++t) { ka[t] = kb[t]; ga[t] = gb2[t]; }
    }
}

// ---------------- Kernel 3: barrier-free wave-independent consumer ------------
// 1024 blocks x 4 waves x 2 sequential chunks. All cross-lane data via shfl
// (r19-verified) or wave-private LDS slot a_s[wv] (no block barriers).
__global__ __launch_bounds__(256)
void k3_seq(const float* __restrict__ Qp, const float* __restrict__ Kp,
            const float* __restrict__ Vp, const float* __restrict__ Gp,
            const ushort* __restrict__ S0b, float* __restrict__ Op)
{
    __shared__ __align__(16) ushort a_s[4][L][40];   // masked Gram, wave-private

    const int tid = threadIdx.x;
    const int wv = tid >> 6;
    const int lane = tid & 63;
    const int half = lane >> 5;
    const int m = lane & 31;
    const int wid = blockIdx.x * 4 + wv;             // 4096 waves

    for (int cc = 0; cc < 2; ++cc) {
        const int chunk = wid * 2 + cc;
        const int bh = chunk >> 7;
        const int c = chunk & (NC - 1);
        const int b = bh >> 4;
        const int h = bh & (H - 1);
        const long base = ((long)b * S + (long)c * L) * RS + h * D;
        const ushort* S0c = S0b + (long)chunk * (D * D);

        // Q/K fragments (row-major b128)
        const float* qrow = Qp + base + (long)m * RS + 8 * half;
        const float* krow = Kp + base + (long)m * RS + 8 * half;
        float4 qv0 = *(const float4*)(qrow);
        float4 qv1 = *(const float4*)(qrow + 4);
        float4 qv2 = *(const float4*)(qrow + 16);
        float4 qv3 = *(const float4*)(qrow + 20);
        float4 kv0 = *(const float4*)(krow);
        float4 kv1 = *(const float4*)(krow + 4);
        float4 kv2 = *(const float4*)(krow + 16);
        float4 kv3 = *(const float4*)(krow + 20);
        short8v qa0, qa1, ka0, ka1;
        {
            float qf[16] = {qv0.x,qv0.y,qv0.z,qv0.w, qv1.x,qv1.y,qv1.z,qv1.w,
                            qv2.x,qv2.y,qv2.z,qv2.w, qv3.x,qv3.y,qv3.z,qv3.w};
            float kf[16] = {kv0.x,kv0.y,kv0.z,kv0.w, kv1.x,kv1.y,kv1.z,kv1.w,
                            kv2.x,kv2.y,kv2.z,kv2.w, kv3.x,kv3.y,kv3.z,kv3.w};
            #pragma unroll
            for (int e = 0; e < 8; ++e) {
                qa0[e] = f2bf(qf[e]);     qa1[e] = f2bf(qf[8 + e]);
                ka0[e] = f2bf(kf[e]);     ka1[e] = f2bf(kf[8 + e]);
            }
        }

        // per-lane register cumsum of own half-column; cross-half via shfl (r19)
        float cum[16];
        {
            const float* gcol = Gp + base + (long)(half * 16) * RS + m;
            float run = 0.f;
            #pragma unroll
            for (int t = 0; t < 16; ++t) {
                run += flog2(fmaxf(gcol[(long)t * RS], GEPS));
                cum[t] = run;
            }
        }
        {
            const float oth = __shfl_xor(cum[15], 32);
            if (half) {
                #pragma unroll
                for (int t = 0; t < 16; ++t) cum[t] += oth;
            }
        }
        const float c7 = cum[7], c15 = cum[15];
        const float o7 = __shfl_xor(c7, 32), o15 = __shfl_xor(c15, 32);
        float es4[4];
        es4[0] = half ? o7  : c7;
        es4[1] = half ? o15 : c15;
        es4[2] = half ? c7  : o7;
        es4[3] = half ? c15 : o15;

        // li at C-rows via 8 paired exchanges (r19-verified)
        float li[16];
        #pragma unroll
        for (int j = 0; j < 8; ++j) {
            const int tl = (j & 3) + 8 * (j >> 2);     // 0..3, 8..11
            const float send = half ? cum[tl] : cum[tl + 4];
            const float recv = __shfl_xor(send, 32);
            li[j]     = half ? recv        : cum[tl];
            li[j + 8] = half ? cum[tl + 4] : recv;
        }

        // W (SUB-scaled) in registers + half-exchange -> B-fragments (r19)
        unsigned wpk[8];
        {
            const float* vcol = Vp + base + (long)(half * 16) * RS + m;
            #pragma unroll
            for (int j = 0; j < 8; ++j) {
                const int t0 = 2 * j, t1 = 2 * j + 1;
                const float e0 = (t0 < 8) ? c7 : c15;
                const float e1 = (t1 < 8) ? c7 : c15;
                const float w0 = vcol[(long)t0 * RS] * fexp2(e0 - cum[t0]);
                const float w1 = vcol[(long)t1 * RS] * fexp2(e1 - cum[t1]);
                wpk[j] = f2bfu(w0) | (f2bfu(w1) << 16);
            }
        }
        short8v wfk0, wfk1;
        {
            unsigned xf[4], rc[4];
            #pragma unroll
            for (int j = 0; j < 4; ++j) xf[j] = half ? wpk[j] : wpk[4 + j];
            #pragma unroll
            for (int j = 0; j < 4; ++j) rc[j] = (unsigned)__shfl_xor((int)xf[j], 32);
            uint4 w0u, w1u;
            w0u.x = half ? rc[0] : wpk[0];  w0u.y = half ? rc[1] : wpk[1];
            w0u.z = half ? rc[2] : wpk[2];  w0u.w = half ? rc[3] : wpk[3];
            w1u.x = half ? wpk[4] : rc[0];  w1u.y = half ? wpk[5] : rc[1];
            w1u.z = half ? wpk[6] : rc[2];  w1u.w = half ? wpk[7] : rc[3];
            wfk0 = *(short8v*)&w0u;
            wfk1 = *(short8v*)&w1u;
        }

        // Gram A = Q.K^T -> masked bf16 a_s (wave-private; no block barrier)
        {
            f32x16 acc;
            #pragma unroll
            for (int e = 0; e < 16; ++e) acc[e] = 0.f;
            acc = __builtin_amdgcn_mfma_f32_32x32x16_bf16(qa0, ka0, acc, 0, 0, 0);
            acc = __builtin_amdgcn_mfma_f32_32x32x16_bf16(qa1, ka1, acc, 0, 0, 0);
            #pragma unroll
            for (int reg = 0; reg < 16; ++reg) {
                const int irow = (reg & 3) + 8 * (reg >> 2) + 4 * half;
                const float av = (m <= irow) ? acc[reg] : 0.f;
                a_s[wv][irow][m] = (ushort)f2bf(av);
            }
        }

        // cross-chunk: 2^{l_i} * (Q.S0), S0 bf16 from global
        f32x16 sacc;
        #pragma unroll
        for (int e = 0; e < 16; ++e) sacc[e] = 0.f;
        {
            short8v sf0, sf1;
            #pragma unroll
            for (int e = 0; e < 8; ++e) {
                sf0[e] = (short)S0c[(8 * half + e) * D + m];
                sf1[e] = (short)S0c[(16 + 8 * half + e) * D + m];
            }
            sacc = __builtin_amdgcn_mfma_f32_32x32x16_bf16(qa0, sf0, sacc, 0, 0, 0);
            sacc = __builtin_amdgcn_mfma_f32_32x32x16_bf16(qa1, sf1, sacc, 0, 0, 0);
        }
        f32x16 out;
        #pragma unroll
        for (int reg = 0; reg < 16; ++reg) out[reg] = fexp2(li[reg]) * sacc[reg];

        // intra-chunk P (a_s read after same-wave write: program order)
        #pragma unroll
        for (int ks = 0; ks < 2; ++ks) {
            const short8v af = *(const short8v*)&a_s[wv][m][16 * ks + 8 * half];
            const short8v wf = ks ? wfk1 : wfk0;
            #pragma unroll
            for (int par = 0; par < 2; ++par) {
                const int s = 2 * ks + par;
                short8v am;
                #pragma unroll
                for (int e = 0; e < 8; ++e) am[e] = (half == par) ? af[e] : (short)0;
                f32x16 p;
                #pragma unroll
                for (int e = 0; e < 16; ++e) p[e] = 0.f;
                p = __builtin_amdgcn_mfma_f32_32x32x16_bf16(am, wf, p, 0, 0, 0);
                #pragma unroll
                for (int reg = 0; reg < 16; ++reg)
                    out[reg] += fexp2(fminf(li[reg] - es4[s], 120.f)) * p[reg];
            }
        }

        #pragma unroll
        for (int reg = 0; reg < 16; ++reg) {
            const int irow = (reg & 3) + 8 * (reg >> 2) + 4 * half;
            Op[base + (long)irow * RS + m] = out[reg];
        }
    }
}

} // namespace

extern "C" void kernel_launch(void* const* d_in, const int* in_sizes, int n_in,
                              void* d_out, int out_size, void* d_ws, size_t ws_size,
                              hipStream_t stream)
{
    const float* q = (const float*)d_in[0];
    const float* k = (const float*)d_in[1];
    const float* v = (const float*)d_in[2];
    const float* g = (const float*)d_in[3];
    float* out = (float*)d_out;

    ushort* ChKV = (ushort*)d_ws;                          // [8192][1024] bf16 (16.8 MB)
    float* ChG = (float*)(ChKV + (long)NBH * NC * D * D);  // [8192][32] f32   (1.05 MB)

    dim3 blk(256);
    k1_seq<<<dim3(NBH * 8), blk, 0, stream>>>(k, v, g, ChKV, ChG);
    k2_scan<<<dim3(NBH * 4), blk, 0, stream>>>(ChKV, ChG);
    k3_seq<<<dim3(NBH * NC / 8), blk, 0, stream>>>(q, k, v, g, ChKV, out);
}

// Round 24
// 63.609 us; speedup vs baseline: 1.0653x; 1.0653x over previous
//
#include <hip/hip_runtime.h>

namespace {

constexpr int B = 4, S = 4096, H = 16, D = 32;
constexpr int L = 32;             // chunk length
constexpr int NC = S / L;         // 128 chunks per sequence
constexpr int NBH = B * H;        // 64
constexpr int RS = H * D;         // 512 floats between consecutive time steps
constexpr float GEPS = 1.52587890625e-05f;  // 2^-16 per-step decay clamp

// Lore (rounds 6-23, measured):
//  - launch_bounds(256,w) caps VGPR ~256/w; cap < live set => GB-scale spill.
//  - Scalar j-loops over LDS tiles are LDS-instruction bound -> MFMA.
//  - COLD scalar column loads are latency death (r13); OK L3-warm (r12).
//  - Pure consumers beat recomputing consumers for STATE (r16-19); exports
//    merely conserve k1+k3 (r20-22). k3_seq (barrier-free, shfl cross-lane,
//    wave-private a_s) is the best consumer (~15us, r23).
//  - r23: sequential-loop k1 at 512 blocks = 2 blocks/CU -> occupancy 18%,
//    43us. Sequential structure is fine but needs residency: 2048 blocks x
//    4 chunks = 8 blocks/CU (13.3KB LDS, 48 VGPR -> full occupancy).
//  - NEVER quantize l below f32 (r21 absmax 1.5); scales/W in bf16 are fine.
//  - MFMA operand convention (HW-verified r12, absmax 0.5):
//    A-op: row = lane&31, k = 8*(lane>>5)+e (+16 for 2nd MFMA)
//    B-op: col = lane&31, same k
//    C/D : col = lane&31, row = (reg&3)+8*(reg>>2)+4*(lane>>5)

typedef __attribute__((ext_vector_type(8)))  short short8v;   // 8 bf16 = 4 VGPR
typedef __attribute__((ext_vector_type(16))) float f32x16;    // 16 f32 acc

__device__ __forceinline__ float flog2(float x) { return __builtin_amdgcn_logf(x); }
__device__ __forceinline__ float fexp2(float x) { return __builtin_amdgcn_exp2f(x); }
__device__ __forceinline__ unsigned f2bfu(float f) {          // fp32 -> bf16 (RNE)
    unsigned u = __float_as_uint(f);
    return (u + 0x7FFFu + ((u >> 16) & 1u)) >> 16;
}
__device__ __forceinline__ short f2bf(float f) { return (short)f2bfu(f); }
__device__ __forceinline__ float bf2f(short s) {              // bf16 -> fp32
    return __uint_as_float(((unsigned)(ushort)s) << 16);
}

// ---------------- Kernel 1: sequential-chunk producer, full residency ---------
// 2048 blocks x 4 chunks sequential (8 blocks/CU). Loads at loop-top hide HBM
// latency under previous iteration's compute.
// W = v*2^{total-l};  ChKV[chunk] bf16;  ChG[chunk] = 2^{total}.
__global__ __launch_bounds__(256)
void k1_seq(const float* __restrict__ Kp, const float* __restrict__ Vp,
            const float* __restrict__ Gp, ushort* __restrict__ ChKV,
            float* __restrict__ ChG)
{
    __shared__ __align__(16) float  k_s[L][36];
    __shared__ __align__(16) float  lg[L][36];
    __shared__ __align__(16) ushort w_s[L][40];
    __shared__ float sub[8][D];
    __shared__ float totr[D];

    const int blk = blockIdx.x;              // bh*32 + seg
    const int bh = blk >> 5, seg = blk & 31;
    const int b = bh >> 4, h = bh & (H - 1);

    const int tid = threadIdx.x;
    const int i = tid >> 3;                  // row 0..31
    const int u = (tid & 7) * 4;             // col quad
    const int m = tid & 31, t = tid >> 5;    // scan mapping
    const int r0 = t * 4;

    for (int cc = 0; cc < 4; ++cc) {
        const int c = seg * 4 + cc;
        const int chunk = bh * NC + c;
        const long base = ((long)b * S + (long)c * L) * RS + h * D;
        const long roff = base + (long)i * RS + u;
        float4 k4 = *(const float4*)(Kp + roff);       // issued before barrier:
        float4 v4 = *(const float4*)(Vp + roff);       // overlaps prev compute
        float4 g4 = *(const float4*)(Gp + roff);
        __syncthreads();                     // prev iteration LDS consumed
        *(float4*)&k_s[i][u] = k4;
        float4 lv;
        lv.x = flog2(fmaxf(g4.x, GEPS));
        lv.y = flog2(fmaxf(g4.y, GEPS));
        lv.z = flog2(fmaxf(g4.z, GEPS));
        lv.w = flog2(fmaxf(g4.w, GEPS));
        *(float4*)&lg[i][u] = lv;
        __syncthreads();                     // b1

        float c0 = lg[r0 + 0][m];
        float c1 = c0 + lg[r0 + 1][m];
        float c2 = c1 + lg[r0 + 2][m];
        float c3 = c2 + lg[r0 + 3][m];
        sub[t][m] = c3;
        __syncthreads();                     // b2

        {
            float sb[8];
            float total = 0.f;
            #pragma unroll
            for (int tt = 0; tt < 8; ++tt) { sb[tt] = sub[tt][m]; total += sb[tt]; }
            float base_l = 0.f;
            #pragma unroll
            for (int tt = 0; tt < 8; ++tt) { if (tt < t) base_l += sb[tt]; }
            lg[r0 + 0][m] = base_l + c0;
            lg[r0 + 1][m] = base_l + c1;
            lg[r0 + 2][m] = base_l + c2;
            lg[r0 + 3][m] = base_l + c3;
            if (t == 0) totr[m] = total;
            if (t == 1) ChG[(long)chunk * D + m] = fexp2(total);
        }
        __syncthreads();                     // b3

        // W = v * 2^{total - l}  (exponent <= 0), v4 still in registers
        {
            float4 l4 = *(float4*)&lg[i][u];
            float4 t4 = *(float4*)&totr[u];
            unsigned p0 = f2bfu(v4.x * fexp2(t4.x - l4.x))
                        | (f2bfu(v4.y * fexp2(t4.y - l4.y)) << 16);
            unsigned p1 = f2bfu(v4.z * fexp2(t4.z - l4.z))
                        | (f2bfu(v4.w * fexp2(t4.w - l4.w)) << 16);
            uint2 pp; pp.x = p0; pp.y = p1;
            *(uint2*)&w_s[i][u] = pp;
        }
        __syncthreads();                     // b4

        // wave 0: 2 MFMAs + bf16 store (waves 1-3 run ahead to next loads)
        if (tid < 64) {
            const int half = tid >> 5;
            const int mm = tid & 31;
            short8v ka0, ka1, wf0, wf1;
            #pragma unroll
            for (int e = 0; e < 8; ++e) {
                ka0[e] = f2bf(k_s[8 * half + e][mm]);
                ka1[e] = f2bf(k_s[16 + 8 * half + e][mm]);
                wf0[e] = (short)w_s[8 * half + e][mm];
                wf1[e] = (short)w_s[16 + 8 * half + e][mm];
            }
            f32x16 acc;
            #pragma unroll
            for (int e = 0; e < 16; ++e) acc[e] = 0.f;
            acc = __builtin_amdgcn_mfma_f32_32x32x16_bf16(ka0, wf0, acc, 0, 0, 0);
            acc = __builtin_amdgcn_mfma_f32_32x32x16_bf16(ka1, wf1, acc, 0, 0, 0);

            ushort* kvout = ChKV + (long)chunk * (D * D);
            #pragma unroll
            for (int reg = 0; reg < 16; ++reg) {
                const int d = (reg & 3) + 8 * (reg >> 2) + 4 * half;
                kvout[d * D + mm] = (ushort)f2bf(acc[reg]);
            }
        }
    }
}

// ---------------- Kernel 2: inter-chunk scan (bf16 in/out, f32 state) --------
__global__ __launch_bounds__(256)
void k2_scan(ushort* __restrict__ ChKV, const float* __restrict__ ChG)
{
    const int bh = blockIdx.x >> 2;
    const int dg = blockIdx.x & 3;
    const int tid = threadIdx.x;
    const int d = dg * 8 + (tid >> 5);
    const int m = tid & 31;

    const long kvoff = (long)bh * NC * (D * D) + d * D + m;
    const long goff = (long)bh * NC * D + m;

    ushort ka[8]; float ga[8];
    #pragma unroll
    for (int t = 0; t < 8; ++t) {
        ka[t] = ChKV[kvoff + (long)t * (D * D)];
        ga[t] = ChG[goff + (long)t * D];
    }
    float st = 0.f;
    for (int c0 = 0; c0 < NC; c0 += 8) {
        ushort kb[8]; float gb2[8];
        const bool more = (c0 + 8) < NC;
        #pragma unroll
        for (int t = 0; t < 8; ++t) {
            kb[t]  = more ? ChKV[kvoff + (long)(c0 + 8 + t) * (D * D)] : (ushort)0;
            gb2[t] = more ? ChG[goff + (long)(c0 + 8 + t) * D] : 0.f;
        }
        #pragma unroll
        for (int t = 0; t < 8; ++t) {
            ChKV[kvoff + (long)(c0 + t) * (D * D)] = (ushort)f2bf(st); // START
            st = ga[t] * st + bf2f((short)ka[t]);
        }
        #pragma unroll
        for (int t = 0; t < 8; ++t) { ka[t] = kb[t]; ga[t] = gb2[t]; }
    }
}

// ---------------- Kernel 3: barrier-free wave-independent consumer ------------
// 1024 blocks x 4 waves x 2 sequential chunks (r23-verified, ~15us).
__global__ __launch_bounds__(256)
void k3_seq(const float* __restrict__ Qp, const float* __restrict__ Kp,
            const float* __restrict__ Vp, const float* __restrict__ Gp,
            const ushort* __restrict__ S0b, float* __restrict__ Op)
{
    __shared__ __align__(16) ushort a_s[4][L][40];   // masked Gram, wave-private

    const int tid = threadIdx.x;
    const int wv = tid >> 6;
    const int lane = tid & 63;
    const int half = lane >> 5;
    const int m = lane & 31;
    const int wid = blockIdx.x * 4 + wv;             // 4096 waves

    for (int cc = 0; cc < 2; ++cc) {
        const int chunk = wid * 2 + cc;
        const int bh = chunk >> 7;
        const int c = chunk & (NC - 1);
        const int b = bh >> 4;
        const int h = bh & (H - 1);
        const long base = ((long)b * S + (long)c * L) * RS + h * D;
        const ushort* S0c = S0b + (long)chunk * (D * D);

        // Q/K fragments (row-major b128)
        const float* qrow = Qp + base + (long)m * RS + 8 * half;
        const float* krow = Kp + base + (long)m * RS + 8 * half;
        float4 qv0 = *(const float4*)(qrow);
        float4 qv1 = *(const float4*)(qrow + 4);
        float4 qv2 = *(const float4*)(qrow + 16);
        float4 qv3 = *(const float4*)(qrow + 20);
        float4 kv0 = *(const float4*)(krow);
        float4 kv1 = *(const float4*)(krow + 4);
        float4 kv2 = *(const float4*)(krow + 16);
        float4 kv3 = *(const float4*)(krow + 20);
        short8v qa0, qa1, ka0, ka1;
        {
            float qf[16] = {qv0.x,qv0.y,qv0.z,qv0.w, qv1.x,qv1.y,qv1.z,qv1.w,
                            qv2.x,qv2.y,qv2.z,qv2.w, qv3.x,qv3.y,qv3.z,qv3.w};
            float kf[16] = {kv0.x,kv0.y,kv0.z,kv0.w, kv1.x,kv1.y,kv1.z,kv1.w,
                            kv2.x,kv2.y,kv2.z,kv2.w, kv3.x,kv3.y,kv3.z,kv3.w};
            #pragma unroll
            for (int e = 0; e < 8; ++e) {
                qa0[e] = f2bf(qf[e]);     qa1[e] = f2bf(qf[8 + e]);
                ka0[e] = f2bf(kf[e]);     ka1[e] = f2bf(kf[8 + e]);
            }
        }

        // per-lane register cumsum of own half-column; cross-half via shfl
        float cum[16];
        {
            const float* gcol = Gp + base + (long)(half * 16) * RS + m;
            float run = 0.f;
            #pragma unroll
            for (int t = 0; t < 16; ++t) {
                run += flog2(fmaxf(gcol[(long)t * RS], GEPS));
                cum[t] = run;
            }
        }
        {
            const float oth = __shfl_xor(cum[15], 32);
            if (half) {
                #pragma unroll
                for (int t = 0; t < 16; ++t) cum[t] += oth;
            }
        }
        const float c7 = cum[7], c15 = cum[15];
        const float o7 = __shfl_xor(c7, 32), o15 = __shfl_xor(c15, 32);
        float es4[4];
        es4[0] = half ? o7  : c7;
        es4[1] = half ? o15 : c15;
        es4[2] = half ? c7  : o7;
        es4[3] = half ? c15 : o15;

        // li at C-rows via 8 paired exchanges
        float li[16];
        #pragma unroll
        for (int j = 0; j < 8; ++j) {
            const int tl = (j & 3) + 8 * (j >> 2);     // 0..3, 8..11
            const float send = half ? cum[tl] : cum[tl + 4];
            const float recv = __shfl_xor(send, 32);
            li[j]     = half ? recv        : cum[tl];
            li[j + 8] = half ? cum[tl + 4] : recv;
        }

        // W (SUB-scaled) in registers + half-exchange -> B-fragments
        unsigned wpk[8];
        {
            const float* vcol = Vp + base + (long)(half * 16) * RS + m;
            #pragma unroll
            for (int j = 0; j < 8; ++j) {
                const int t0 = 2 * j, t1 = 2 * j + 1;
                const float e0 = (t0 < 8) ? c7 : c15;
                const float e1 = (t1 < 8) ? c7 : c15;
                const float w0 = vcol[(long)t0 * RS] * fexp2(e0 - cum[t0]);
                const float w1 = vcol[(long)t1 * RS] * fexp2(e1 - cum[t1]);
                wpk[j] = f2bfu(w0) | (f2bfu(w1) << 16);
            }
        }
        short8v wfk0, wfk1;
        {
            unsigned xf[4], rc[4];
            #pragma unroll
            for (int j = 0; j < 4; ++j) xf[j] = half ? wpk[j] : wpk[4 + j];
            #pragma unroll
            for (int j = 0; j < 4; ++j) rc[j] = (unsigned)__shfl_xor((int)xf[j], 32);
            uint4 w0u, w1u;
            w0u.x = half ? rc[0] : wpk[0];  w0u.y = half ? rc[1] : wpk[1];
            w0u.z = half ? rc[2] : wpk[2];  w0u.w = half ? rc[3] : wpk[3];
            w1u.x = half ? wpk[4] : rc[0];  w1u.y = half ? wpk[5] : rc[1];
            w1u.z = half ? wpk[6] : rc[2];  w1u.w = half ? wpk[7] : rc[3];
            wfk0 = *(short8v*)&w0u;
            wfk1 = *(short8v*)&w1u;
        }

        // Gram A = Q.K^T -> masked bf16 a_s (wave-private; no block barrier)
        {
            f32x16 acc;
            #pragma unroll
            for (int e = 0; e < 16; ++e) acc[e] = 0.f;
            acc = __builtin_amdgcn_mfma_f32_32x32x16_bf16(qa0, ka0, acc, 0, 0, 0);
            acc = __builtin_amdgcn_mfma_f32_32x32x16_bf16(qa1, ka1, acc, 0, 0, 0);
            #pragma unroll
            for (int reg = 0; reg < 16; ++reg) {
                const int irow = (reg & 3) + 8 * (reg >> 2) + 4 * half;
                const float av = (m <= irow) ? acc[reg] : 0.f;
                a_s[wv][irow][m] = (ushort)f2bf(av);
            }
        }

        // cross-chunk: 2^{l_i} * (Q.S0), S0 bf16 from global
        f32x16 sacc;
        #pragma unroll
        for (int e = 0; e < 16; ++e) sacc[e] = 0.f;
        {
            short8v sf0, sf1;
            #pragma unroll
            for (int e = 0; e < 8; ++e) {
                sf0[e] = (short)S0c[(8 * half + e) * D + m];
                sf1[e] = (short)S0c[(16 + 8 * half + e) * D + m];
            }
            sacc = __builtin_amdgcn_mfma_f32_32x32x16_bf16(qa0, sf0, sacc, 0, 0, 0);
            sacc = __builtin_amdgcn_mfma_f32_32x32x16_bf16(qa1, sf1, sacc, 0, 0, 0);
        }
        f32x16 out;
        #pragma unroll
        for (int reg = 0; reg < 16; ++reg) out[reg] = fexp2(li[reg]) * sacc[reg];

        // intra-chunk P (a_s read after same-wave write: program order)
        #pragma unroll
        for (int ks = 0; ks < 2; ++ks) {
            const short8v af = *(const short8v*)&a_s[wv][m][16 * ks + 8 * half];
            const short8v wf = ks ? wfk1 : wfk0;
            #pragma unroll
            for (int par = 0; par < 2; ++par) {
                const int s = 2 * ks + par;
                short8v am;
                #pragma unroll
                for (int e = 0; e < 8; ++e) am[e] = (half == par) ? af[e] : (short)0;
                f32x16 p;
                #pragma unroll
                for (int e = 0; e < 16; ++e) p[e] = 0.f;
                p = __builtin_amdgcn_mfma_f32_32x32x16_bf16(am, wf, p, 0, 0, 0);
                #pragma unroll
                for (int reg = 0; reg < 16; ++reg)
                    out[reg] += fexp2(fminf(li[reg] - es4[s], 120.f)) * p[reg];
            }
        }

        #pragma unroll
        for (int reg = 0; reg < 16; ++reg) {
            const int irow = (reg & 3) + 8 * (reg >> 2) + 4 * half;
            Op[base + (long)irow * RS + m] = out[reg];
        }
    }
}

} // namespace

extern "C" void kernel_launch(void* const* d_in, const int* in_sizes, int n_in,
                              void* d_out, int out_size, void* d_ws, size_t ws_size,
                              hipStream_t stream)
{
    const float* q = (const float*)d_in[0];
    const float* k = (const float*)d_in[1];
    const float* v = (const float*)d_in[2];
    const float* g = (const float*)d_in[3];
    float* out = (float*)d_out;

    ushort* ChKV = (ushort*)d_ws;                          // [8192][1024] bf16 (16.8 MB)
    float* ChG = (float*)(ChKV + (long)NBH * NC * D * D);  // [8192][32] f32   (1.05 MB)

    dim3 blk(256);
    k1_seq<<<dim3(NBH * 32), blk, 0, stream>>>(k, v, g, ChKV, ChG);
    k2_scan<<<dim3(NBH * 4), blk, 0, stream>>>(ChKV, ChG);
    k3_seq<<<dim3(NBH * NC / 8), blk, 0, stream>>>(q, k, v, g, ChKV, out);
}

// Round 25
// 61.594 us; speedup vs baseline: 1.1002x; 1.0327x over previous
//
#include <hip/hip_runtime.h>

namespace {

constexpr int B = 4, S = 4096, H = 16, D = 32;
constexpr int L = 32;             // chunk length
constexpr int NC = S / L;         // 128 chunks per sequence
constexpr int NBH = B * H;        // 64
constexpr int RS = H * D;         // 512 floats between consecutive time steps
constexpr float GEPS = 1.52587890625e-05f;  // 2^-16 per-step decay clamp

// Lore (rounds 6-24, measured):
//  - launch_bounds(256,w) caps VGPR ~256/w; cap < live set => GB-scale spill.
//  - Scalar j-loops over LDS tiles are LDS-instruction bound -> MFMA.
//  - COLD scalar column loads are latency death (r13) BUT in steady-state
//    graph replay the 134MB input set is L3-resident (k1 FETCH=49MB of 100MB
//    read) -> column loads fine (k3_seq: 48 col loads/lane, 15us).
//  - Block-cooperative k1 (5 barriers/chunk, wave0-only MFMA tail) is
//    schedule-bound at ~35-44us REGARDLESS of grid/occupancy (r20-24).
//    Wave-independent barrier-free kernels (k3_seq pattern) are the fix.
//  - NEVER quantize l below f32 (r21 absmax 1.5); scales/W in bf16 are fine.
//  - MFMA operand convention (HW-verified r12, absmax 0.5):
//    A-op: row = lane&31, k = 8*(lane>>5)+e (+16 for 2nd MFMA)
//    B-op: col = lane&31, same k
//    C/D : col = lane&31, row = (reg&3)+8*(reg>>2)+4*(lane>>5)

typedef __attribute__((ext_vector_type(8)))  short short8v;   // 8 bf16 = 4 VGPR
typedef __attribute__((ext_vector_type(16))) float f32x16;    // 16 f32 acc

__device__ __forceinline__ float flog2(float x) { return __builtin_amdgcn_logf(x); }
__device__ __forceinline__ float fexp2(float x) { return __builtin_amdgcn_exp2f(x); }
__device__ __forceinline__ unsigned f2bfu(float f) {          // fp32 -> bf16 (RNE)
    unsigned u = __float_as_uint(f);
    return (u + 0x7FFFu + ((u >> 16) & 1u)) >> 16;
}
__device__ __forceinline__ short f2bf(float f) { return (short)f2bfu(f); }
__device__ __forceinline__ float bf2f(short s) {              // bf16 -> fp32
    return __uint_as_float(((unsigned)(ushort)s) << 16);
}

// ---------------- Kernel 1: wave-independent barrier-free producer ------------
// 2048 blocks x 4 waves x 1 chunk. Zero LDS, zero barriers.
// K A-frag via column loads; G cumsum + cross-half shfl; W=v*2^{total-l} in
// registers + half-exchange -> B-frags; 2 MFMAs -> ChKV bf16; ChG=2^{total}.
__global__ __launch_bounds__(256)
void k1_wave(const float* __restrict__ Kp, const float* __restrict__ Vp,
             const float* __restrict__ Gp, ushort* __restrict__ ChKV,
             float* __restrict__ ChG)
{
    const int tid = threadIdx.x;
    const int wv = tid >> 6;
    const int lane = tid & 63;
    const int half = lane >> 5;
    const int m = lane & 31;

    const int chunk = blockIdx.x * 4 + wv;
    const int bh = chunk >> 7;
    const int c = chunk & (NC - 1);
    const int b = bh >> 4;
    const int h = bh & (H - 1);
    const long base = ((long)b * S + (long)c * L) * RS + h * D;

    // K A-fragment: A[d=m][k=j] = K[j][m]  (column loads; r13-verified layout)
    short8v ka0, ka1;
    {
        const float* kcol = Kp + base + m;
        #pragma unroll
        for (int e = 0; e < 8; ++e) {
            ka0[e] = f2bf(kcol[(long)(8 * half + e) * RS]);
            ka1[e] = f2bf(kcol[(long)(16 + 8 * half + e) * RS]);
        }
    }

    // per-lane register cumsum of own half-column; cross-half via shfl (r19)
    float cum[16];
    {
        const float* gcol = Gp + base + (long)(half * 16) * RS + m;
        float run = 0.f;
        #pragma unroll
        for (int t = 0; t < 16; ++t) {
            run += flog2(fmaxf(gcol[(long)t * RS], GEPS));
            cum[t] = run;
        }
    }
    {
        const float oth = __shfl_xor(cum[15], 32);
        if (half) {
            #pragma unroll
            for (int t = 0; t < 16; ++t) cum[t] += oth;
        }
    }
    const float c15 = cum[15];
    const float o15 = __shfl_xor(c15, 32);
    const float total = half ? c15 : o15;    // full-chunk l (most negative)

    // W = v * 2^{total - l}  (exponent <= 0), packed bf16 pairs in registers
    unsigned wpk[8];
    {
        const float* vcol = Vp + base + (long)(half * 16) * RS + m;
        #pragma unroll
        for (int j = 0; j < 8; ++j) {
            const int t0 = 2 * j, t1 = 2 * j + 1;
            const float w0 = vcol[(long)t0 * RS] * fexp2(total - cum[t0]);
            const float w1 = vcol[(long)t1 * RS] * fexp2(total - cum[t1]);
            wpk[j] = f2bfu(w0) | (f2bfu(w1) << 16);
        }
    }
    // half-exchange -> B-fragments (r19-verified pattern)
    short8v wf0, wf1;
    {
        unsigned xf[4], rc[4];
        #pragma unroll
        for (int j = 0; j < 4; ++j) xf[j] = half ? wpk[j] : wpk[4 + j];
        #pragma unroll
        for (int j = 0; j < 4; ++j) rc[j] = (unsigned)__shfl_xor((int)xf[j], 32);
        uint4 w0u, w1u;
        w0u.x = half ? rc[0] : wpk[0];  w0u.y = half ? rc[1] : wpk[1];
        w0u.z = half ? rc[2] : wpk[2];  w0u.w = half ? rc[3] : wpk[3];
        w1u.x = half ? wpk[4] : rc[0];  w1u.y = half ? wpk[5] : rc[1];
        w1u.z = half ? wpk[6] : rc[2];  w1u.w = half ? wpk[7] : rc[3];
        wf0 = *(short8v*)&w0u;
        wf1 = *(short8v*)&w1u;
    }

    // ChKV[d][m] = sum_j K[j][d] * W[j][m]  (2 MFMAs)
    f32x16 acc;
    #pragma unroll
    for (int e = 0; e < 16; ++e) acc[e] = 0.f;
    acc = __builtin_amdgcn_mfma_f32_32x32x16_bf16(ka0, wf0, acc, 0, 0, 0);
    acc = __builtin_amdgcn_mfma_f32_32x32x16_bf16(ka1, wf1, acc, 0, 0, 0);

    ushort* kvout = ChKV + (long)chunk * (D * D);
    #pragma unroll
    for (int reg = 0; reg < 16; ++reg) {
        const int d = (reg & 3) + 8 * (reg >> 2) + 4 * half;
        kvout[d * D + m] = (ushort)f2bf(acc[reg]);
    }
    if (half) ChG[(long)chunk * D + m] = fexp2(c15);
}

// ---------------- Kernel 2: inter-chunk scan (bf16 in/out, f32 state) --------
__global__ __launch_bounds__(256)
void k2_scan(ushort* __restrict__ ChKV, const float* __restrict__ ChG)
{
    const int bh = blockIdx.x >> 2;
    const int dg = blockIdx.x & 3;
    const int tid = threadIdx.x;
    const int d = dg * 8 + (tid >> 5);
    const int m = tid & 31;

    const long kvoff = (long)bh * NC * (D * D) + d * D + m;
    const long goff = (long)bh * NC * D + m;

    ushort ka[8]; float ga[8];
    #pragma unroll
    for (int t = 0; t < 8; ++t) {
        ka[t] = ChKV[kvoff + (long)t * (D * D)];
        ga[t] = ChG[goff + (long)t * D];
    }
    float st = 0.f;
    for (int c0 = 0; c0 < NC; c0 += 8) {
        ushort kb[8]; float gb2[8];
        const bool more = (c0 + 8) < NC;
        #pragma unroll
        for (int t = 0; t < 8; ++t) {
            kb[t]  = more ? ChKV[kvoff + (long)(c0 + 8 + t) * (D * D)] : (ushort)0;
            gb2[t] = more ? ChG[goff + (long)(c0 + 8 + t) * D] : 0.f;
        }
        #pragma unroll
        for (int t = 0; t < 8; ++t) {
            ChKV[kvoff + (long)(c0 + t) * (D * D)] = (ushort)f2bf(st); // START
            st = ga[t] * st + bf2f((short)ka[t]);
        }
        #pragma unroll
        for (int t = 0; t < 8; ++t) { ka[t] = kb[t]; ga[t] = gb2[t]; }
    }
}

// ---------------- Kernel 3: barrier-free wave-independent consumer ------------
// 1024 blocks x 4 waves x 2 sequential chunks (r23/r24-verified, ~15us).
__global__ __launch_bounds__(256)
void k3_seq(const float* __restrict__ Qp, const float* __restrict__ Kp,
            const float* __restrict__ Vp, const float* __restrict__ Gp,
            const ushort* __restrict__ S0b, float* __restrict__ Op)
{
    __shared__ __align__(16) ushort a_s[4][L][40];   // masked Gram, wave-private

    const int tid = threadIdx.x;
    const int wv = tid >> 6;
    const int lane = tid & 63;
    const int half = lane >> 5;
    const int m = lane & 31;
    const int wid = blockIdx.x * 4 + wv;             // 4096 waves

    for (int cc = 0; cc < 2; ++cc) {
        const int chunk = wid * 2 + cc;
        const int bh = chunk >> 7;
        const int c = chunk & (NC - 1);
        const int b = bh >> 4;
        const int h = bh & (H - 1);
        const long base = ((long)b * S + (long)c * L) * RS + h * D;
        const ushort* S0c = S0b + (long)chunk * (D * D);

        // Q/K fragments (row-major b128)
        const float* qrow = Qp + base + (long)m * RS + 8 * half;
        const float* krow = Kp + base + (long)m * RS + 8 * half;
        float4 qv0 = *(const float4*)(qrow);
        float4 qv1 = *(const float4*)(qrow + 4);
        float4 qv2 = *(const float4*)(qrow + 16);
        float4 qv3 = *(const float4*)(qrow + 20);
        float4 kv0 = *(const float4*)(krow);
        float4 kv1 = *(const float4*)(krow + 4);
        float4 kv2 = *(const float4*)(krow + 16);
        float4 kv3 = *(const float4*)(krow + 20);
        short8v qa0, qa1, ka0, ka1;
        {
            float qf[16] = {qv0.x,qv0.y,qv0.z,qv0.w, qv1.x,qv1.y,qv1.z,qv1.w,
                            qv2.x,qv2.y,qv2.z,qv2.w, qv3.x,qv3.y,qv3.z,qv3.w};
            float kf[16] = {kv0.x,kv0.y,kv0.z,kv0.w, kv1.x,kv1.y,kv1.z,kv1.w,
                            kv2.x,kv2.y,kv2.z,kv2.w, kv3.x,kv3.y,kv3.z,kv3.w};
            #pragma unroll
            for (int e = 0; e < 8; ++e) {
                qa0[e] = f2bf(qf[e]);     qa1[e] = f2bf(qf[8 + e]);
                ka0[e] = f2bf(kf[e]);     ka1[e] = f2bf(kf[8 + e]);
            }
        }

        // per-lane register cumsum of own half-column; cross-half via shfl
        float cum[16];
        {
            const float* gcol = Gp + base + (long)(half * 16) * RS + m;
            float run = 0.f;
            #pragma unroll
            for (int t = 0; t < 16; ++t) {
                run += flog2(fmaxf(gcol[(long)t * RS], GEPS));
                cum[t] = run;
            }
        }
        {
            const float oth = __shfl_xor(cum[15], 32);
            if (half) {
                #pragma unroll
                for (int t = 0; t < 16; ++t) cum[t] += oth;
            }
        }
        const float c7 = cum[7], c15 = cum[15];
        const float o7 = __shfl_xor(c7, 32), o15 = __shfl_xor(c15, 32);
        float es4[4];
        es4[0] = half ? o7  : c7;
        es4[1] = half ? o15 : c15;
        es4[2] = half ? c7  : o7;
        es4[3] = half ? c15 : o15;

        // li at C-rows via 8 paired exchanges
        float li[16];
        #pragma unroll
        for (int j = 0; j < 8; ++j) {
            const int tl = (j & 3) + 8 * (j >> 2);     // 0..3, 8..11
            const float send = half ? cum[tl] : cum[tl + 4];
            const float recv = __shfl_xor(send, 32);
            li[j]     = half ? recv        : cum[tl];
            li[j + 8] = half ? cum[tl + 4] : recv;
        }

        // W (SUB-scaled) in registers + half-exchange -> B-fragments
        unsigned wpk[8];
        {
            const float* vcol = Vp + base + (long)(half * 16) * RS + m;
            #pragma unroll
            for (int j = 0; j < 8; ++j) {
                const int t0 = 2 * j, t1 = 2 * j + 1;
                const float e0 = (t0 < 8) ? c7 : c15;
                const float e1 = (t1 < 8) ? c7 : c15;
                const float w0 = vcol[(long)t0 * RS] * fexp2(e0 - cum[t0]);
                const float w1 = vcol[(long)t1 * RS] * fexp2(e1 - cum[t1]);
                wpk[j] = f2bfu(w0) | (f2bfu(w1) << 16);
            }
        }
        short8v wfk0, wfk1;
        {
            unsigned xf[4], rc[4];
            #pragma unroll
            for (int j = 0; j < 4; ++j) xf[j] = half ? wpk[j] : wpk[4 + j];
            #pragma unroll
            for (int j = 0; j < 4; ++j) rc[j] = (unsigned)__shfl_xor((int)xf[j], 32);
            uint4 w0u, w1u;
            w0u.x = half ? rc[0] : wpk[0];  w0u.y = half ? rc[1] : wpk[1];
            w0u.z = half ? rc[2] : wpk[2];  w0u.w = half ? rc[3] : wpk[3];
            w1u.x = half ? wpk[4] : rc[0];  w1u.y = half ? wpk[5] : rc[1];
            w1u.z = half ? wpk[6] : rc[2];  w1u.w = half ? wpk[7] : rc[3];
            wfk0 = *(short8v*)&w0u;
            wfk1 = *(short8v*)&w1u;
        }

        // Gram A = Q.K^T -> masked bf16 a_s (wave-private; no block barrier)
        {
            f32x16 acc;
            #pragma unroll
            for (int e = 0; e < 16; ++e) acc[e] = 0.f;
            acc = __builtin_amdgcn_mfma_f32_32x32x16_bf16(qa0, ka0, acc, 0, 0, 0);
            acc = __builtin_amdgcn_mfma_f32_32x32x16_bf16(qa1, ka1, acc, 0, 0, 0);
            #pragma unroll
            for (int reg = 0; reg < 16; ++reg) {
                const int irow = (reg & 3) + 8 * (reg >> 2) + 4 * half;
                const float av = (m <= irow) ? acc[reg] : 0.f;
                a_s[wv][irow][m] = (ushort)f2bf(av);
            }
        }

        // cross-chunk: 2^{l_i} * (Q.S0), S0 bf16 from global
        f32x16 sacc;
        #pragma unroll
        for (int e = 0; e < 16; ++e) sacc[e] = 0.f;
        {
            short8v sf0, sf1;
            #pragma unroll
            for (int e = 0; e < 8; ++e) {
                sf0[e] = (short)S0c[(8 * half + e) * D + m];
                sf1[e] = (short)S0c[(16 + 8 * half + e) * D + m];
            }
            sacc = __builtin_amdgcn_mfma_f32_32x32x16_bf16(qa0, sf0, sacc, 0, 0, 0);
            sacc = __builtin_amdgcn_mfma_f32_32x32x16_bf16(qa1, sf1, sacc, 0, 0, 0);
        }
        f32x16 out;
        #pragma unroll
        for (int reg = 0; reg < 16; ++reg) out[reg] = fexp2(li[reg]) * sacc[reg];

        // intra-chunk P (a_s read after same-wave write: program order)
        #pragma unroll
        for (int ks = 0; ks < 2; ++ks) {
            const short8v af = *(const short8v*)&a_s[wv][m][16 * ks + 8 * half];
            const short8v wf = ks ? wfk1 : wfk0;
            #pragma unroll
            for (int par = 0; par < 2; ++par) {
                const int s = 2 * ks + par;
                short8v am;
                #pragma unroll
                for (int e = 0; e < 8; ++e) am[e] = (half == par) ? af[e] : (short)0;
                f32x16 p;
                #pragma unroll
                for (int e = 0; e < 16; ++e) p[e] = 0.f;
                p = __builtin_amdgcn_mfma_f32_32x32x16_bf16(am, wf, p, 0, 0, 0);
                #pragma unroll
                for (int reg = 0; reg < 16; ++reg)
                    out[reg] += fexp2(fminf(li[reg] - es4[s], 120.f)) * p[reg];
            }
        }

        #pragma unroll
        for (int reg = 0; reg < 16; ++reg) {
            const int irow = (reg & 3) + 8 * (reg >> 2) + 4 * half;
            Op[base + (long)irow * RS + m] = out[reg];
        }
    }
}

} // namespace

extern "C" void kernel_launch(void* const* d_in, const int* in_sizes, int n_in,
                              void* d_out, int out_size, void* d_ws, size_t ws_size,
                              hipStream_t stream)
{
    const float* q = (const float*)d_in[0];
    const float* k = (const float*)d_in[1];
    const float* v = (const float*)d_in[2];
    const float* g = (const float*)d_in[3];
    float* out = (float*)d_out;

    ushort* ChKV = (ushort*)d_ws;                          // [8192][1024] bf16 (16.8 MB)
    float* ChG = (float*)(ChKV + (long)NBH * NC * D * D);  // [8192][32] f32   (1.05 MB)

    dim3 blk(256);
    k1_wave<<<dim3(NBH * NC / 4), blk, 0, stream>>>(k, v, g, ChKV, ChG);
    k2_scan<<<dim3(NBH * 4), blk, 0, stream>>>(ChKV, ChG);
    k3_seq<<<dim3(NBH * NC / 8), blk, 0, stream>>>(q, k, v, g, ChKV, out);
}